// Round 1
// baseline (485.090 us; speedup 1.0000x reference)
//
#include <hip/hip_runtime.h>

typedef _Float16 f16;
typedef _Float16 f16x8 __attribute__((ext_vector_type(8)));
typedef float    f32x4 __attribute__((ext_vector_type(4)));
typedef f16x8 f16x8_a __attribute__((may_alias));
typedef f16   f16_a   __attribute__((may_alias));

#define NN 100000
#define NE 1000000

static __device__ __forceinline__ f32x4 mfma16(f16x8 a, f16x8 b, f32x4 c) {
  return __builtin_amdgcn_mfma_f32_16x16x32_f16(a, b, c, 0, 0, 0);
}

static __device__ __forceinline__ f16x8 zero8() {
  f16x8 z; 
#pragma unroll
  for (int j = 0; j < 8; ++j) z[j] = (f16)0.f;
  return z;
}

// ---- LDS staging with XOR swizzle (byte ^= (row&7)<<4) ----
// Weights are stored transposed in global: W^T[n][k], row bytes = K*2 (power of 2).
template<int RB_LOG2, int SZ>
static __device__ __forceinline__ void load_weights(const f16* __restrict__ gw, char* lds) {
  const char* src = (const char*)gw;
#pragma unroll
  for (int g = threadIdx.x; g < SZ / 16; g += 256) {
    int byte = g << 4;
    int row  = byte >> RB_LOG2;
    int dstb = byte ^ ((row & 7) << 4);
    f16x8 v = *(const f16x8_a*)(src + byte);
    *(f16x8_a*)(lds + dstb) = v;
  }
}

template<int RB_LOG2>
static __device__ __forceinline__ f16x8 read_b(const char* lds, int n, int kbyte) {
  int byte = ((n << RB_LOG2) + kbyte) ^ ((n & 7) << 4);
  return *(const f16x8_a*)(lds + byte);
}

// per-wave activation tile: 32 rows x 128 f16 (256B rows), swizzled
static __device__ __forceinline__ f16x8 act_read(const char* act, int base, int m, int kbyte) {
  int byte = (base + m * 256 + kbyte) ^ ((m & 7) << 4);
  return *(const f16x8_a*)(act + byte);
}

static __device__ __forceinline__ void act_write(char* act, int base, int m, int col, f16 v) {
  int byte = (base + m * 256 + col * 2) ^ ((m & 7) << 4);
  *(f16_a*)(act + byte) = v;
}

// ---------------- weight transpose+cast prep ----------------
__global__ void transpose_w(const float* __restrict__ src, f16* __restrict__ dst,
                            int K, int N, int kOff, int ld) {
  int i = blockIdx.x * 256 + threadIdx.x;
  if (i >= N * K) return;
  int n = i / K, k = i - n * K;
  dst[i] = (f16)src[(size_t)(kOff + k) * ld + n];
}

// ---------------- node encoder ----------------
__global__ __launch_bounds__(256, 2) void node_kernel(
    const float* __restrict__ nf, const f16* __restrict__ WnT1, const float* __restrict__ bn1,
    const f16* __restrict__ WnT2, const float* __restrict__ bn2, f16* __restrict__ emb) {
  __shared__ char wbuf[32768];
  __shared__ char act[32768];
  const int tid = threadIdx.x, w = tid >> 6, lane = tid & 63;
  const int c = lane & 15, kb = lane >> 4;
  const int base = blockIdx.x * 128 + w * 32;
  const int abase = w * 8192;

  load_weights<8, 32768>(WnT1, wbuf);
  __syncthreads();

  // A fragments from node_features (f32 -> f16)
  f16x8 a[2][4];
#pragma unroll
  for (int rt = 0; rt < 2; ++rt) {
    int r = base + rt * 16 + c; r = r < NN ? r : 0;
    const float* p = nf + (size_t)r * 128 + kb * 8;
#pragma unroll
    for (int ks = 0; ks < 4; ++ks) {
      float4 x0 = *(const float4*)(p + ks * 32);
      float4 x1 = *(const float4*)(p + ks * 32 + 4);
      f16x8 t;
      t[0]=(f16)x0.x; t[1]=(f16)x0.y; t[2]=(f16)x0.z; t[3]=(f16)x0.w;
      t[4]=(f16)x1.x; t[5]=(f16)x1.y; t[6]=(f16)x1.z; t[7]=(f16)x1.w;
      a[rt][ks] = t;
    }
  }

  f32x4 acc[2][8];
#pragma unroll
  for (int nt = 0; nt < 8; ++nt) {
    float bb = bn1[nt * 16 + c];
    acc[0][nt] = f32x4{bb, bb, bb, bb};
    acc[1][nt] = f32x4{bb, bb, bb, bb};
  }
#pragma unroll
  for (int ks = 0; ks < 4; ++ks)
#pragma unroll
    for (int nt = 0; nt < 8; ++nt) {
      f16x8 b = read_b<8>(wbuf, nt * 16 + c, ks * 64 + kb * 16);
      acc[0][nt] = mfma16(a[0][ks], b, acc[0][nt]);
      acc[1][nt] = mfma16(a[1][ks], b, acc[1][nt]);
    }
#pragma unroll
  for (int rt = 0; rt < 2; ++rt)
#pragma unroll
    for (int nt = 0; nt < 8; ++nt)
#pragma unroll
      for (int r = 0; r < 4; ++r) {
        float v = acc[rt][nt][r];
        v = v > 0.f ? v : 0.f;
        act_write(act, abase, rt * 16 + kb * 4 + r, nt * 16 + c, (f16)v);
      }

  __syncthreads();
  load_weights<8, 32768>(WnT2, wbuf);
  __syncthreads();

  f32x4 acc2[2][8];
#pragma unroll
  for (int nt = 0; nt < 8; ++nt) {
    float bb = bn2[nt * 16 + c];
    acc2[0][nt] = f32x4{bb, bb, bb, bb};
    acc2[1][nt] = f32x4{bb, bb, bb, bb};
  }
#pragma unroll
  for (int ks = 0; ks < 4; ++ks) {
    f16x8 a0 = act_read(act, abase, c,      ks * 64 + kb * 16);
    f16x8 a1 = act_read(act, abase, 16 + c, ks * 64 + kb * 16);
#pragma unroll
    for (int nt = 0; nt < 8; ++nt) {
      f16x8 b = read_b<8>(wbuf, nt * 16 + c, ks * 64 + kb * 16);
      acc2[0][nt] = mfma16(a0, b, acc2[0][nt]);
      acc2[1][nt] = mfma16(a1, b, acc2[1][nt]);
    }
  }
#pragma unroll
  for (int rt = 0; rt < 2; ++rt)
#pragma unroll
    for (int nt = 0; nt < 8; ++nt)
#pragma unroll
      for (int r = 0; r < 4; ++r) {
        int row = base + rt * 16 + kb * 4 + r;
        if (row < NN) emb[(size_t)row * 128 + nt * 16 + c] = (f16)acc2[rt][nt][r];
      }
}

// ---------------- fused edge pipeline ----------------
__global__ __launch_bounds__(256, 2) void edge_kernel(
    const float* __restrict__ ef, const int* __restrict__ eidx,
    const f16* __restrict__ emb,
    const f16* __restrict__ WeT1, const float* __restrict__ be1,
    const f16* __restrict__ WeT2, const float* __restrict__ be2,
    const f16* __restrict__ Wp1a, const f16* __restrict__ Wp1b, const f16* __restrict__ Wp1c,
    const float* __restrict__ bp1,
    const f16* __restrict__ WpT2, const float* __restrict__ bp2,
    const float* __restrict__ Wp3, const float* __restrict__ bp3,
    float* __restrict__ out) {
  __shared__ char wbuf[32768];
  __shared__ char act[32768];
  const int tid = threadIdx.x, w = tid >> 6, lane = tid & 63;
  const int c = lane & 15, kb = lane >> 4;
  const int ebase = blockIdx.x * 128 + w * 32;
  const int abase = w * 8192;

  // ---- E1: edge features [*,16] -> 128, relu ----
  load_weights<5, 4096>(WeT1, wbuf);
  __syncthreads();
  {
    f16x8 a[2];
#pragma unroll
    for (int rt = 0; rt < 2; ++rt) {
      int m = ebase + rt * 16 + c; m = m < NE ? m : 0;
      f16x8 t = zero8();
      if (kb < 2) {
        const float* p = ef + (size_t)m * 16 + kb * 8;
        float4 x0 = *(const float4*)(p);
        float4 x1 = *(const float4*)(p + 4);
        t[0]=(f16)x0.x; t[1]=(f16)x0.y; t[2]=(f16)x0.z; t[3]=(f16)x0.w;
        t[4]=(f16)x1.x; t[5]=(f16)x1.y; t[6]=(f16)x1.z; t[7]=(f16)x1.w;
      }
      a[rt] = t;
    }
    f32x4 acc[2][8];
#pragma unroll
    for (int nt = 0; nt < 8; ++nt) {
      float bb = be1[nt * 16 + c];
      acc[0][nt] = f32x4{bb, bb, bb, bb};
      acc[1][nt] = f32x4{bb, bb, bb, bb};
    }
    int kbyte = (kb < 2) ? kb * 16 : 0;
#pragma unroll
    for (int nt = 0; nt < 8; ++nt) {
      f16x8 b = read_b<5>(wbuf, nt * 16 + c, kbyte);
      acc[0][nt] = mfma16(a[0], b, acc[0][nt]);
      acc[1][nt] = mfma16(a[1], b, acc[1][nt]);
    }
#pragma unroll
    for (int rt = 0; rt < 2; ++rt)
#pragma unroll
      for (int nt = 0; nt < 8; ++nt)
#pragma unroll
        for (int r = 0; r < 4; ++r) {
          float v = acc[rt][nt][r];
          v = v > 0.f ? v : 0.f;
          act_write(act, abase, rt * 16 + kb * 4 + r, nt * 16 + c, (f16)v);
        }
  }

  // ---- E2: h1 @ WeT2 + be2 (no relu) -> edge_emb ----
  __syncthreads();
  load_weights<8, 32768>(WeT2, wbuf);
  __syncthreads();
  {
    f32x4 acc[2][8];
#pragma unroll
    for (int nt = 0; nt < 8; ++nt) {
      float bb = be2[nt * 16 + c];
      acc[0][nt] = f32x4{bb, bb, bb, bb};
      acc[1][nt] = f32x4{bb, bb, bb, bb};
    }
#pragma unroll
    for (int ks = 0; ks < 4; ++ks) {
      f16x8 a0 = act_read(act, abase, c,      ks * 64 + kb * 16);
      f16x8 a1 = act_read(act, abase, 16 + c, ks * 64 + kb * 16);
#pragma unroll
      for (int nt = 0; nt < 8; ++nt) {
        f16x8 b = read_b<8>(wbuf, nt * 16 + c, ks * 64 + kb * 16);
        acc[0][nt] = mfma16(a0, b, acc[0][nt]);
        acc[1][nt] = mfma16(a1, b, acc[1][nt]);
      }
    }
#pragma unroll
    for (int rt = 0; rt < 2; ++rt)
#pragma unroll
      for (int nt = 0; nt < 8; ++nt)
#pragma unroll
        for (int r = 0; r < 4; ++r)
          act_write(act, abase, rt * 16 + kb * 4 + r, nt * 16 + c, (f16)acc[rt][nt][r]);
  }

  // ---- P1: src@Wp1a + dst@Wp1b + edge@Wp1c + bp1, relu ----
  f32x4 accp[2][8];
#pragma unroll
  for (int nt = 0; nt < 8; ++nt) {
    float bb = bp1[nt * 16 + c];
    accp[0][nt] = f32x4{bb, bb, bb, bb};
    accp[1][nt] = f32x4{bb, bb, bb, bb};
  }

  // P1a: src gather
  __syncthreads();
  load_weights<8, 32768>(Wp1a, wbuf);
  __syncthreads();
  {
    f16x8 a[2][4];
#pragma unroll
    for (int rt = 0; rt < 2; ++rt) {
      int m = ebase + rt * 16 + c; m = m < NE ? m : NE - 1;
      int s = eidx[m];
      const f16* np = emb + (size_t)s * 128 + kb * 8;
#pragma unroll
      for (int ks = 0; ks < 4; ++ks) a[rt][ks] = *(const f16x8_a*)(np + ks * 32);
    }
#pragma unroll
    for (int ks = 0; ks < 4; ++ks)
#pragma unroll
      for (int nt = 0; nt < 8; ++nt) {
        f16x8 b = read_b<8>(wbuf, nt * 16 + c, ks * 64 + kb * 16);
        accp[0][nt] = mfma16(a[0][ks], b, accp[0][nt]);
        accp[1][nt] = mfma16(a[1][ks], b, accp[1][nt]);
      }
  }

  // P1b: dst gather
  __syncthreads();
  load_weights<8, 32768>(Wp1b, wbuf);
  __syncthreads();
  {
    f16x8 a[2][4];
#pragma unroll
    for (int rt = 0; rt < 2; ++rt) {
      int m = ebase + rt * 16 + c; m = m < NE ? m : NE - 1;
      int s = eidx[NE + m];
      const f16* np = emb + (size_t)s * 128 + kb * 8;
#pragma unroll
      for (int ks = 0; ks < 4; ++ks) a[rt][ks] = *(const f16x8_a*)(np + ks * 32);
    }
#pragma unroll
    for (int ks = 0; ks < 4; ++ks)
#pragma unroll
      for (int nt = 0; nt < 8; ++nt) {
        f16x8 b = read_b<8>(wbuf, nt * 16 + c, ks * 64 + kb * 16);
        accp[0][nt] = mfma16(a[0][ks], b, accp[0][nt]);
        accp[1][nt] = mfma16(a[1][ks], b, accp[1][nt]);
      }
  }

  // P1c: edge_emb from act
  __syncthreads();
  load_weights<8, 32768>(Wp1c, wbuf);
  __syncthreads();
  {
#pragma unroll
    for (int ks = 0; ks < 4; ++ks) {
      f16x8 a0 = act_read(act, abase, c,      ks * 64 + kb * 16);
      f16x8 a1 = act_read(act, abase, 16 + c, ks * 64 + kb * 16);
#pragma unroll
      for (int nt = 0; nt < 8; ++nt) {
        f16x8 b = read_b<8>(wbuf, nt * 16 + c, ks * 64 + kb * 16);
        accp[0][nt] = mfma16(a0, b, accp[0][nt]);
        accp[1][nt] = mfma16(a1, b, accp[1][nt]);
      }
    }
    // relu -> act (h1p)
#pragma unroll
    for (int rt = 0; rt < 2; ++rt)
#pragma unroll
      for (int nt = 0; nt < 8; ++nt)
#pragma unroll
        for (int r = 0; r < 4; ++r) {
          float v = accp[rt][nt][r];
          v = v > 0.f ? v : 0.f;
          act_write(act, abase, rt * 16 + kb * 4 + r, nt * 16 + c, (f16)v);
        }
  }

  // ---- P2: h1p @ WpT2 + bp2 ----
  __syncthreads();
  load_weights<8, 16384>(WpT2, wbuf);
  __syncthreads();
  f32x4 accq[2][4];
#pragma unroll
  for (int nt = 0; nt < 4; ++nt) {
    float bb = bp2[nt * 16 + c];
    accq[0][nt] = f32x4{bb, bb, bb, bb};
    accq[1][nt] = f32x4{bb, bb, bb, bb};
  }
#pragma unroll
  for (int ks = 0; ks < 4; ++ks) {
    f16x8 a0 = act_read(act, abase, c,      ks * 64 + kb * 16);
    f16x8 a1 = act_read(act, abase, 16 + c, ks * 64 + kb * 16);
#pragma unroll
    for (int nt = 0; nt < 4; ++nt) {
      f16x8 b = read_b<8>(wbuf, nt * 16 + c, ks * 64 + kb * 16);
      accq[0][nt] = mfma16(a0, b, accq[0][nt]);
      accq[1][nt] = mfma16(a1, b, accq[1][nt]);
    }
  }

  // ---- P3: relu, dot with Wp3, sigmoid ----
  float w3[4], b3 = bp3[0];
#pragma unroll
  for (int nt = 0; nt < 4; ++nt) w3[nt] = Wp3[nt * 16 + c];
#pragma unroll
  for (int rt = 0; rt < 2; ++rt) {
#pragma unroll
    for (int r = 0; r < 4; ++r) {
      float s = 0.f;
#pragma unroll
      for (int nt = 0; nt < 4; ++nt) {
        float h = accq[rt][nt][r];
        h = h > 0.f ? h : 0.f;
        s += h * w3[nt];
      }
      s += __shfl_xor(s, 1, 64);
      s += __shfl_xor(s, 2, 64);
      s += __shfl_xor(s, 4, 64);
      s += __shfl_xor(s, 8, 64);
      int m = ebase + rt * 16 + kb * 4 + r;
      if (c == r && m < NE) {
        out[m] = 1.f / (1.f + __expf(-(s + b3)));
      }
    }
  }
}

extern "C" void kernel_launch(void* const* d_in, const int* in_sizes, int n_in,
                              void* d_out, int out_size, void* d_ws, size_t ws_size,
                              hipStream_t stream) {
  const float* nf  = (const float*)d_in[0];
  const int*   ei  = (const int*)  d_in[1];
  const float* ef  = (const float*)d_in[2];
  const float* Wn1 = (const float*)d_in[3];
  const float* bn1 = (const float*)d_in[4];
  const float* Wn2 = (const float*)d_in[5];
  const float* bn2 = (const float*)d_in[6];
  const float* We1 = (const float*)d_in[7];
  const float* be1 = (const float*)d_in[8];
  const float* We2 = (const float*)d_in[9];
  const float* be2 = (const float*)d_in[10];
  const float* Wp1 = (const float*)d_in[11];
  const float* bp1 = (const float*)d_in[12];
  const float* Wp2 = (const float*)d_in[13];
  const float* bp2 = (const float*)d_in[14];
  const float* Wp3 = (const float*)d_in[15];
  const float* bp3 = (const float*)d_in[16];

  char* ws = (char*)d_ws;
  f16* WnT1 = (f16*)(ws);
  f16* WnT2 = (f16*)(ws + 32768);
  f16* WeT1 = (f16*)(ws + 65536);
  f16* WeT2 = (f16*)(ws + 69632);
  f16* Wp1a = (f16*)(ws + 102400);
  f16* Wp1b = (f16*)(ws + 135168);
  f16* Wp1c = (f16*)(ws + 167936);
  f16* WpT2 = (f16*)(ws + 200704);
  f16* emb  = (f16*)(ws + 217088);

  transpose_w<<<64, 256, 0, stream>>>(Wn1, WnT1, 128, 128, 0, 128);
  transpose_w<<<64, 256, 0, stream>>>(Wn2, WnT2, 128, 128, 0, 128);
  transpose_w<<<8,  256, 0, stream>>>(We1, WeT1, 16,  128, 0, 128);
  transpose_w<<<64, 256, 0, stream>>>(We2, WeT2, 128, 128, 0, 128);
  transpose_w<<<64, 256, 0, stream>>>(Wp1, Wp1a, 128, 128, 0,   128);
  transpose_w<<<64, 256, 0, stream>>>(Wp1, Wp1b, 128, 128, 128, 128);
  transpose_w<<<64, 256, 0, stream>>>(Wp1, Wp1c, 128, 128, 256, 128);
  transpose_w<<<32, 256, 0, stream>>>(Wp2, WpT2, 128, 64, 0, 64);

  node_kernel<<<782, 256, 0, stream>>>(nf, WnT1, bn1, WnT2, bn2, emb);
  edge_kernel<<<7813, 256, 0, stream>>>(ef, ei, emb, WeT1, be1, WeT2, be2,
                                        Wp1a, Wp1b, Wp1c, bp1, WpT2, bp2, Wp3, bp3,
                                        (float*)d_out);
}